// Round 17
// baseline (277.366 us; speedup 1.0000x reference)
//
#include <hip/hip_runtime.h>

#define NCH 256   // channels (c_in == c_hid == 256)
#define NS  16    // pool slices per graph

typedef short short8 __attribute__((ext_vector_type(8)));
typedef float f32x4  __attribute__((ext_vector_type(4)));

__device__ __forceinline__ float b2f(unsigned short u) {
    union { unsigned int i; float f; } x; x.i = ((unsigned int)u) << 16; return x.f;
}
__device__ __forceinline__ unsigned short f2b(float f) {
    unsigned int u = __float_as_uint(f);
    unsigned int r = (u + 0x7FFFu + ((u >> 16) & 1u)) >> 16;   // RNE
    return (unsigned short)r;
}

#define GLOAD_LDS16(gptr, lptr) \
    __builtin_amdgcn_global_load_lds((const __attribute__((address_space(1))) void*)(gptr), \
                                     (__attribute__((address_space(3))) void*)(lptr), 16, 0, 0)

// ---------------- W transpose-cast + deg zeroing ----------------
__global__ __launch_bounds__(256) void k_castT(const float* __restrict__ W1,
                                               const float* __restrict__ W2,
                                               unsigned short* __restrict__ Wt1,
                                               unsigned short* __restrict__ Wt2,
                                               int* __restrict__ deg, int M) {
    int k = blockIdx.x, n = threadIdx.x;
    const float* W = blockIdx.y ? W2 : W1;
    unsigned short* Wt = blockIdx.y ? Wt2 : Wt1;
    Wt[(size_t)n * 256 + k] = f2b(W[(size_t)k * 256 + n]);
    int gid = (blockIdx.y * 256 + blockIdx.x) * 256 + threadIdx.x;  // 131072 >= M
    if (gid < M) deg[gid] = 0;
}

// ---------------- CSR build ----------------
__global__ __launch_bounds__(256) void k_scan_blk(const int* __restrict__ deg,
                                                  int* __restrict__ part,
                                                  int* __restrict__ bsum, int N) {
    __shared__ int sm[256];
    int t = threadIdx.x;
    int base = blockIdx.x * 1024 + t * 4;
    int v[4]; int s = 0;
#pragma unroll
    for (int j = 0; j < 4; ++j) {
        int i = base + j;
        int d = (i < N) ? deg[i] : 0;
        v[j] = d; s += d;
    }
    sm[t] = s; __syncthreads();
#pragma unroll
    for (int off = 1; off < 256; off <<= 1) {
        int u = (t >= off) ? sm[t - off] : 0;
        __syncthreads();
        sm[t] += u;
        __syncthreads();
    }
    int excl = sm[t] - s;
#pragma unroll
    for (int j = 0; j < 4; ++j) {
        int i = base + j;
        if (i < N) part[i] = excl;
        excl += v[j];
    }
    if (t == 255) bsum[blockIdx.x] = sm[255];
}

// finalize: block's 1024-chunk index cb = blockIdx>>2 is uniform; compute
// boff = sum bsum[0..cb) with one wave (nb <= 64), then finish row_ptr/cursor/dinv.
__global__ __launch_bounds__(256) void k_finalize(const int* __restrict__ deg,
                                                  int* __restrict__ row_ptr,
                                                  const int* __restrict__ bsum,
                                                  int* __restrict__ cursor,
                                                  float* __restrict__ dinv,
                                                  int N, int E) {
    __shared__ int sboff;
    const int cb = blockIdx.x >> 2;
    if (threadIdx.x < 64) {
        int v = (threadIdx.x < cb) ? bsum[threadIdx.x] : 0;
#pragma unroll
        for (int m = 1; m < 64; m <<= 1) v += __shfl_xor(v, m, 64);
        if (threadIdx.x == 0) sboff = v;
    }
    __syncthreads();
    int i = blockIdx.x * 256 + threadIdx.x;
    if (i < N) {
        int rp = row_ptr[i] + sboff;
        row_ptr[i] = rp;
        cursor[i]  = rp;
        dinv[i] = rsqrtf((float)(deg[i] + 1));   // +1: self-loop
    }
    if (blockIdx.x == 0 && threadIdx.x == 0) row_ptr[N] = E;  // sum(deg) == E
}

// Sharded scatter: block b -> chunk b>>3, shard b&7 of dst space.
__global__ __launch_bounds__(256) void k_scatter_sh(const int* __restrict__ src,
                                                    const int* __restrict__ dst, int E,
                                                    int* __restrict__ cursor,
                                                    const float* __restrict__ dinv,
                                                    int2* __restrict__ cw,
                                                    unsigned shmul) {
    const int shard  = blockIdx.x & 7;
    const int nchunk = gridDim.x >> 3;
    const int chunk  = blockIdx.x >> 3;
    const int per = (E + nchunk - 1) / nchunk;
    const int e0 = chunk * per;
    const int e1 = min(e0 + per, E);
    for (int e = e0 + threadIdx.x; e < e1; e += 256) {
        int d = dst[e];
        int s = (int)__umulhi((unsigned)d, shmul);
        if (s == shard) {
            int sv = src[e];
            int pos = atomicAdd(&cursor[d], 1);
            cw[pos] = make_int2(sv, __float_as_int(dinv[sv]));
        }
    }
}

// ---------------- shared GEMM pieces ----------------
__device__ __forceinline__ void load_bfr(const unsigned short* __restrict__ Bt,
                                         short8 bfr[2][8], int w, int lr, int ku) {
    const unsigned short* pb = Bt + (size_t)(w * 32 + lr) * NCH + ku * 8;
#pragma unroll
    for (int nf = 0; nf < 2; ++nf)
#pragma unroll
        for (int ks = 0; ks < 8; ++ks)
            bfr[nf][ks] = *(const short8*)(pb + nf * 16 * NCH + ks * 32);
}

__device__ __forceinline__ void gemm_compute_store(const unsigned short* As,
                                                   const short8 bfr[2][8],
                                                   unsigned short* __restrict__ C,
                                                   int M, int t, int w, int lr, int ku) {
    f32x4 acc[2][2];
#pragma unroll
    for (int rf = 0; rf < 2; ++rf)
#pragma unroll
        for (int nf = 0; nf < 2; ++nf) acc[rf][nf] = (f32x4){0.f, 0.f, 0.f, 0.f};

#pragma unroll
    for (int ks = 0; ks < 8; ++ks) {
#pragma unroll
        for (int rf = 0; rf < 2; ++rf) {
            int row = rf * 16 + lr;
            int uu  = (ks * 4 + ku) ^ (row & 7);
            short8 af = *(const short8*)&As[row * 256 + uu * 8];
            acc[rf][0] = __builtin_amdgcn_mfma_f32_16x16x32_bf16(bfr[0][ks], af,
                                                                 acc[rf][0], 0, 0, 0);
            acc[rf][1] = __builtin_amdgcn_mfma_f32_16x16x32_bf16(bfr[1][ks], af,
                                                                 acc[rf][1], 0, 0, 0);
        }
    }

#pragma unroll
    for (int rf = 0; rf < 2; ++rf) {
        int row = t * 32 + rf * 16 + lr;
        if (row < M) {
            unsigned short* pc = C + (size_t)row * NCH + w * 32 + ku * 4;
#pragma unroll
            for (int nf = 0; nf < 2; ++nf) {
                unsigned short us[4];
                us[0] = f2b(acc[rf][nf][0]); us[1] = f2b(acc[rf][nf][1]);
                us[2] = f2b(acc[rf][nf][2]); us[3] = f2b(acc[rf][nf][3]);
                *(int2*)(pc + nf * 16) = *(const int2*)us;
            }
        }
    }
}

// ---------------- layer-2 GEMM: dbuf grid-stride, bf16 A via global_load_lds ----
__global__ __launch_bounds__(512, 4) void k_gemm2(const unsigned short* __restrict__ A,
                                                  const unsigned short* __restrict__ Bt,
                                                  unsigned short* __restrict__ C,
                                                  int M, int tiles) {
    __shared__ unsigned short As[2][32 * 256];
    const int tid  = threadIdx.x;
    const int w    = tid >> 6;
    const int lane = tid & 63;
    const int lr   = lane & 15;
    const int ku   = lane >> 4;

    short8 bfr[2][8];
    load_bfr(Bt, bfr, w, lr, ku);

    const int gu0 = w * 128 + lane;

#define STAGE2(tt, buf) do {                                                  \
        _Pragma("unroll")                                                     \
        for (int j = 0; j < 2; ++j) {                                         \
            int gu = gu0 + j * 64;                                            \
            int r  = gu >> 5;                                                 \
            int u  = gu & 31;                                                 \
            int grow = (tt) * 32 + r; if (grow >= M) grow = M - 1;            \
            const unsigned short* gp = A + (size_t)grow * NCH +               \
                                       ((u ^ (r & 7)) << 3);                  \
            GLOAD_LDS16(gp, (buf) + (size_t)(w * 128 + j * 64) * 8);          \
        }                                                                     \
    } while (0)

    int t = blockIdx.x;
    int cur = 0;
    if (t < tiles) STAGE2(t, As[0]);
    __syncthreads();

    for (; t < tiles; t += gridDim.x) {
        int tn = t + gridDim.x;
        if (tn < tiles) STAGE2(tn, As[cur ^ 1]);
        gemm_compute_store(As[cur], bfr, C, M, t, w, lr, ku);
        __syncthreads();
        cur ^= 1;
    }
#undef STAGE2
}

// ---------------- fused layer-1 GEMM + sharded degree histogram -----------------
__global__ __launch_bounds__(512, 4) void k_g1h(const float* __restrict__ A,
                                                const unsigned short* __restrict__ Bt,
                                                unsigned short* __restrict__ C,
                                                int M, int tiles, int gblocks,
                                                const int* __restrict__ dst, int E,
                                                int* __restrict__ deg,
                                                unsigned shmul) {
    __shared__ unsigned short As[2][32 * 256];
    const int tid = threadIdx.x;

    if (blockIdx.x >= gblocks) {     // ---- hist path (block-uniform branch) ----
        const int b = blockIdx.x - gblocks;
        const int shard  = b & 7;
        const int nchunk = (gridDim.x - gblocks) >> 3;
        const int chunk  = b >> 3;
        const int per = (E + nchunk - 1) / nchunk;
        const int e0 = chunk * per;
        const int e1 = min(e0 + per, E);
        for (int e = e0 + tid; e < e1; e += 512) {
            int d = dst[e];
            if ((int)__umulhi((unsigned)d, shmul) == shard)
                atomicAdd(&deg[d], 1);
        }
        return;
    }

    // ---- gemm1 path (dbuf grid-stride + fused f32->bf16 cast staging) ----
    const int w    = tid >> 6;
    const int lane = tid & 63;
    const int lr   = lane & 15;
    const int ku   = lane >> 4;

    short8 bfr[2][8];
    load_bfr(Bt, bfr, w, lr, ku);

    const int r0_ = tid >> 5,          u0_ = tid & 31;
    const int r1_ = (tid + 512) >> 5,  u1_ = (tid + 512) & 31;

    int t = blockIdx.x;
    int cur = 0;
    if (t < tiles) {                       // prologue: full stage of tile t
        int g0 = t * 32 + r0_; if (g0 >= M) g0 = M - 1;
        int g1 = t * 32 + r1_; if (g1 >= M) g1 = M - 1;
        const float4* pa0 = (const float4*)(A + (size_t)g0 * NCH + u0_ * 8);
        const float4* pa1 = (const float4*)(A + (size_t)g1 * NCH + u1_ * 8);
        float4 a0 = pa0[0], a1 = pa0[1];
        float4 b0 = pa1[0], b1 = pa1[1];
        unsigned short us[8];
        us[0]=f2b(a0.x); us[1]=f2b(a0.y); us[2]=f2b(a0.z); us[3]=f2b(a0.w);
        us[4]=f2b(a1.x); us[5]=f2b(a1.y); us[6]=f2b(a1.z); us[7]=f2b(a1.w);
        *(int4*)&As[0][r0_ * 256 + ((u0_ ^ (r0_ & 7)) << 3)] = *(const int4*)us;
        us[0]=f2b(b0.x); us[1]=f2b(b0.y); us[2]=f2b(b0.z); us[3]=f2b(b0.w);
        us[4]=f2b(b1.x); us[5]=f2b(b1.y); us[6]=f2b(b1.z); us[7]=f2b(b1.w);
        *(int4*)&As[0][r1_ * 256 + ((u1_ ^ (r1_ & 7)) << 3)] = *(const int4*)us;
    }
    __syncthreads();

    for (; t < tiles; t += gblocks) {
        int tn = t + gblocks;
        float4 a0, a1, b0, b1;
        if (tn < tiles) {                  // issue loads early (hide under MFMA)
            int g0 = tn * 32 + r0_; if (g0 >= M) g0 = M - 1;
            int g1 = tn * 32 + r1_; if (g1 >= M) g1 = M - 1;
            const float4* pa0 = (const float4*)(A + (size_t)g0 * NCH + u0_ * 8);
            const float4* pa1 = (const float4*)(A + (size_t)g1 * NCH + u1_ * 8);
            a0 = pa0[0]; a1 = pa0[1];
            b0 = pa1[0]; b1 = pa1[1];
        }

        gemm_compute_store(As[cur], bfr, C, M, t, w, lr, ku);

        if (tn < tiles) {                  // cvt + write late
            unsigned short us[8];
            us[0]=f2b(a0.x); us[1]=f2b(a0.y); us[2]=f2b(a0.z); us[3]=f2b(a0.w);
            us[4]=f2b(a1.x); us[5]=f2b(a1.y); us[6]=f2b(a1.z); us[7]=f2b(a1.w);
            *(int4*)&As[cur ^ 1][r0_ * 256 + ((u0_ ^ (r0_ & 7)) << 3)] = *(const int4*)us;
            us[0]=f2b(b0.x); us[1]=f2b(b0.y); us[2]=f2b(b0.z); us[3]=f2b(b0.w);
            us[4]=f2b(b1.x); us[5]=f2b(b1.y); us[6]=f2b(b1.z); us[7]=f2b(b1.w);
            *(int4*)&As[cur ^ 1][r1_ * 256 + ((u1_ ^ (r1_ & 7)) << 3)] = *(const int4*)us;
        }
        __syncthreads();
        cur ^= 1;
    }
}

// ---------------- aggregation: wave-per-node, 512-thr blocks (8 nodes) ----------
__global__ __launch_bounds__(512) void k_agg_w(const unsigned short* __restrict__ h,
                                               const float* __restrict__ dinv,
                                               const int* __restrict__ row_ptr,
                                               const int2* __restrict__ cw,
                                               const float* __restrict__ bias,
                                               unsigned short* __restrict__ out, int M) {
    int v = blockIdx.x * 8 + (threadIdx.x >> 6);
    if (v >= M) return;                      // no barriers below: safe
    const int lane = threadIdx.x & 63;
    const int half = lane >> 5;
    const int cb   = (lane & 31) << 3;

    float acc[8] = {};
    float dv = dinv[v];

    short8 rs = {};
    if (half == 0) rs = *(const short8*)&h[(size_t)v * NCH + cb];

    int beg = row_ptr[v], end = row_ptr[v + 1];
    int i0 = beg + half * 2;

    short8 r0 = {}, r1 = {};
    float  w0 = 0.f, w1 = 0.f;
    bool b0 = i0 < end, b1 = i0 + 1 < end;
    if (b0) {
        int2 e = cw[i0];
        r0 = *(const short8*)&h[(size_t)e.x * NCH + cb];
        w0 = __int_as_float(e.y);
    }
    if (b1) {
        int2 e = cw[i0 + 1];
        r1 = *(const short8*)&h[(size_t)e.x * NCH + cb];
        w1 = __int_as_float(e.y);
    }

    while (b0) {
        int in = i0 + 4;
        bool n0 = in < end, n1 = in + 1 < end;
        short8 s0 = {}, s1 = {};
        float  x0 = 0.f, x1 = 0.f;
        if (n0) {
            int2 e = cw[in];
            s0 = *(const short8*)&h[(size_t)e.x * NCH + cb];
            x0 = __int_as_float(e.y);
        }
        if (n1) {
            int2 e = cw[in + 1];
            s1 = *(const short8*)&h[(size_t)e.x * NCH + cb];
            x1 = __int_as_float(e.y);
        }
#pragma unroll
        for (int i = 0; i < 8; ++i) acc[i] += w0 * b2f((unsigned short)r0[i]);
#pragma unroll
        for (int i = 0; i < 8; ++i) acc[i] += w1 * b2f((unsigned short)r1[i]);
        r0 = s0; r1 = s1; w0 = x0; w1 = x1; b0 = n0; b1 = n1; i0 = in;
    }

    if (half == 0) {
#pragma unroll
        for (int i = 0; i < 8; ++i) acc[i] += dv * b2f((unsigned short)rs[i]);
    }

#pragma unroll
    for (int i = 0; i < 8; ++i) acc[i] += __shfl_xor(acc[i], 32, 64);

    if (half == 0) {
        f32x4 bl = *(const f32x4*)&bias[cb];
        f32x4 bh = *(const f32x4*)&bias[cb + 4];
        unsigned short us[8];
#pragma unroll
        for (int i = 0; i < 8; ++i) {
            float b = (i < 4) ? bl[i] : bh[i - 4];
            us[i] = f2b(fmaxf(dv * acc[i] + b, 0.0f));
        }
        *(int4*)&out[(size_t)v * NCH + cb] = *(const int4*)us;
    }
}

// ---------------- mean pool, two-phase ----------------
__device__ __forceinline__ int lower_bound_i(const int* a, int n, int key) {
    int lo = 0, hi = n;
    while (lo < hi) {
        int mid = (lo + hi) >> 1;
        if (a[mid] < key) lo = mid + 1; else hi = mid;
    }
    return lo;
}

__global__ __launch_bounds__(64) void k_pool_a(const unsigned short* __restrict__ a,
                                               const int* __restrict__ batch,
                                               float* __restrict__ partial, int N) {
    int g = blockIdx.x, s = blockIdx.y;
    const int lane = threadIdx.x;
    const int half = lane >> 5;
    const int cb   = (lane & 31) << 3;

    int lo = lower_bound_i(batch, N, g);
    int hi = lower_bound_i(batch, N, g + 1);
    int cnt = hi - lo;
    int len = (cnt + NS - 1) / NS;
    int rlo = lo + s * len;
    int rhi = min(rlo + len, hi);

    float acc[8] = {};
    for (int r = rlo + half; r < rhi; r += 2) {
        short8 hv = *(const short8*)&a[(size_t)r * NCH + cb];
#pragma unroll
        for (int i = 0; i < 8; ++i) acc[i] += b2f((unsigned short)hv[i]);
    }
#pragma unroll
    for (int i = 0; i < 8; ++i) acc[i] += __shfl_xor(acc[i], 32, 64);

    if (half == 0) {
        float* p = partial + ((size_t)g * NS + s) * NCH + cb;
        *(f32x4*)p       = (f32x4){acc[0], acc[1], acc[2], acc[3]};
        *(f32x4*)(p + 4) = (f32x4){acc[4], acc[5], acc[6], acc[7]};
    }
}

__global__ __launch_bounds__(256) void k_pool_b(const float* __restrict__ partial,
                                                const int* __restrict__ batch,
                                                float* __restrict__ out, int N) {
    int g = blockIdx.x, ch = threadIdx.x;
    int lo = lower_bound_i(batch, N, g);
    int hi = lower_bound_i(batch, N, g + 1);
    float s = 0.0f;
#pragma unroll
    for (int k = 0; k < NS; ++k)
        s += partial[((size_t)g * NS + k) * NCH + ch];
    out[(size_t)g * NCH + ch] = s / (float)max(hi - lo, 1);
}

// ---------------- host ----------------
extern "C" void kernel_launch(void* const* d_in, const int* in_sizes, int n_in,
                              void* d_out, int out_size, void* d_ws, size_t ws_size,
                              hipStream_t stream) {
    const float* x     = (const float*)d_in[0];
    const int*   ei    = (const int*)d_in[1];
    const int*   batch = (const int*)d_in[2];
    const float* W1    = (const float*)d_in[3];
    const float* b1    = (const float*)d_in[4];
    const float* W2    = (const float*)d_in[5];
    const float* b2    = (const float*)d_in[6];
    float* out = (float*)d_out;

    const int M = in_sizes[0] / NCH;   // 50000
    const int E = in_sizes[1] / 2;     // 800000
    const int* src = ei;
    const int* dst = ei + E;

    char* w = (char*)d_ws;
    auto alloc = [&](size_t bytes) -> void* {
        void* p = (void*)w;
        w += (bytes + 255) & ~(size_t)255;
        return p;
    };
    int*   deg     = (int*)alloc((size_t)M * 4);
    float* dinv    = (float*)alloc((size_t)M * 4);
    int*   row_ptr = (int*)alloc((size_t)(M + 1) * 4);
    int*   cursor  = (int*)alloc((size_t)M * 4);
    int*   bsum    = (int*)alloc(64 * 4);
    int2*  cw      = (int2*)alloc((size_t)E * 8);
    unsigned short* bufP = (unsigned short*)alloc((size_t)M * NCH * 2);
    unsigned short* bufQ = (unsigned short*)alloc((size_t)M * NCH * 2);
    unsigned short* Wt1  = (unsigned short*)alloc((size_t)NCH * NCH * 2);
    unsigned short* Wt2  = (unsigned short*)alloc((size_t)NCH * NCH * 2);
    float* partial = (float*)alloc((size_t)128 * NS * NCH * 4);

    const int nb = (M + 1023) / 1024;
    const unsigned shmul = (unsigned)(((8ull << 32) + M - 1) / (unsigned long long)M);
    const int tiles = (M + 31) / 32;   // 1563
    const int gblocks = 512;           // gemm1 blocks (mult of 8)
    const int hblocks = 2048;          // hist blocks (256 chunks x 8 shards)

    // W transpose-cast + deg zeroing (replaces memset)
    k_castT<<<dim3(256, 2), 256, 0, stream>>>(W1, W2, Wt1, Wt2, deg, M);

    // layer-1 GEMM fused with degree histogram
    k_g1h<<<gblocks + hblocks, 512, 0, stream>>>(x, Wt1, bufP, M, tiles, gblocks,
                                                 dst, E, deg, shmul);
    k_scan_blk<<<nb, 256, 0, stream>>>(deg, row_ptr, bsum, M);
    k_finalize<<<(M + 255) / 256, 256, 0, stream>>>(deg, row_ptr, bsum, cursor,
                                                    dinv, M, E);
    k_scatter_sh<<<2048, 256, 0, stream>>>(src, dst, E, cursor, dinv, cw, shmul);

    const int agrid = (M + 7) / 8;

    k_agg_w<<<agrid, 512, 0, stream>>>(bufP, dinv, row_ptr, cw, b1, bufQ, M);
    // layer 2
    k_gemm2<<<512, 512, 0, stream>>>(bufQ, Wt2, bufP, M, tiles);
    k_agg_w<<<agrid, 512, 0, stream>>>(bufP, dinv, row_ptr, cw, b2, bufQ, M);
    // pool
    k_pool_a<<<dim3(128, NS), 64, 0, stream>>>(bufQ, batch, partial, M);
    k_pool_b<<<128, 256, 0, stream>>>(partial, batch, out, M);
}

// Round 18
// 268.157 us; speedup vs baseline: 1.0343x; 1.0343x over previous
//
#include <hip/hip_runtime.h>

#define NCH 256   // channels (c_in == c_hid == 256)
#define NS  16    // pool slices per graph

typedef short short8 __attribute__((ext_vector_type(8)));
typedef float f32x4  __attribute__((ext_vector_type(4)));

__device__ __forceinline__ float b2f(unsigned short u) {
    union { unsigned int i; float f; } x; x.i = ((unsigned int)u) << 16; return x.f;
}
__device__ __forceinline__ unsigned short f2b(float f) {
    unsigned int u = __float_as_uint(f);
    unsigned int r = (u + 0x7FFFu + ((u >> 16) & 1u)) >> 16;   // RNE
    return (unsigned short)r;
}

#define GLOAD_LDS16(gptr, lptr) \
    __builtin_amdgcn_global_load_lds((const __attribute__((address_space(1))) void*)(gptr), \
                                     (__attribute__((address_space(3))) void*)(lptr), 16, 0, 0)

// ---------------- W transpose-cast + deg zeroing ----------------
__global__ __launch_bounds__(256) void k_castT(const float* __restrict__ W1,
                                               const float* __restrict__ W2,
                                               unsigned short* __restrict__ Wt1,
                                               unsigned short* __restrict__ Wt2,
                                               int* __restrict__ deg, int M) {
    int k = blockIdx.x, n = threadIdx.x;
    const float* W = blockIdx.y ? W2 : W1;
    unsigned short* Wt = blockIdx.y ? Wt2 : Wt1;
    Wt[(size_t)n * 256 + k] = f2b(W[(size_t)k * 256 + n]);
    int gid = (blockIdx.y * 256 + blockIdx.x) * 256 + threadIdx.x;  // 131072 >= M
    if (gid < M) deg[gid] = 0;
}

// ---------------- CSR build ----------------
__global__ __launch_bounds__(256) void k_scan_blk(const int* __restrict__ deg,
                                                  int* __restrict__ part,
                                                  int* __restrict__ bsum, int N) {
    __shared__ int sm[256];
    int t = threadIdx.x;
    int base = blockIdx.x * 1024 + t * 4;
    int v[4]; int s = 0;
#pragma unroll
    for (int j = 0; j < 4; ++j) {
        int i = base + j;
        int d = (i < N) ? deg[i] : 0;
        v[j] = d; s += d;
    }
    sm[t] = s; __syncthreads();
#pragma unroll
    for (int off = 1; off < 256; off <<= 1) {
        int u = (t >= off) ? sm[t - off] : 0;
        __syncthreads();
        sm[t] += u;
        __syncthreads();
    }
    int excl = sm[t] - s;
#pragma unroll
    for (int j = 0; j < 4; ++j) {
        int i = base + j;
        if (i < N) part[i] = excl;
        excl += v[j];
    }
    if (t == 255) bsum[blockIdx.x] = sm[255];
}

// finalize: block's 1024-chunk index cb = blockIdx>>2 is uniform; compute
// boff = sum bsum[0..cb) with one wave (nb <= 64), then finish row_ptr/cursor/dinv.
__global__ __launch_bounds__(256) void k_finalize(const int* __restrict__ deg,
                                                  int* __restrict__ row_ptr,
                                                  const int* __restrict__ bsum,
                                                  int* __restrict__ cursor,
                                                  float* __restrict__ dinv,
                                                  int N, int E) {
    __shared__ int sboff;
    const int cb = blockIdx.x >> 2;
    if (threadIdx.x < 64) {
        int v = (threadIdx.x < cb) ? bsum[threadIdx.x] : 0;
#pragma unroll
        for (int m = 1; m < 64; m <<= 1) v += __shfl_xor(v, m, 64);
        if (threadIdx.x == 0) sboff = v;
    }
    __syncthreads();
    int i = blockIdx.x * 256 + threadIdx.x;
    if (i < N) {
        int rp = row_ptr[i] + sboff;
        row_ptr[i] = rp;
        cursor[i]  = rp;
        dinv[i] = rsqrtf((float)(deg[i] + 1));   // +1: self-loop
    }
    if (blockIdx.x == 0 && threadIdx.x == 0) row_ptr[N] = E;  // sum(deg) == E
}

// Sharded scatter: block b -> chunk b>>3, shard b&7 of dst space.
__global__ __launch_bounds__(256) void k_scatter_sh(const int* __restrict__ src,
                                                    const int* __restrict__ dst, int E,
                                                    int* __restrict__ cursor,
                                                    const float* __restrict__ dinv,
                                                    int2* __restrict__ cw,
                                                    unsigned shmul) {
    const int shard  = blockIdx.x & 7;
    const int nchunk = gridDim.x >> 3;
    const int chunk  = blockIdx.x >> 3;
    const int per = (E + nchunk - 1) / nchunk;
    const int e0 = chunk * per;
    const int e1 = min(e0 + per, E);
    for (int e = e0 + threadIdx.x; e < e1; e += 256) {
        int d = dst[e];
        int s = (int)__umulhi((unsigned)d, shmul);
        if (s == shard) {
            int sv = src[e];
            int pos = atomicAdd(&cursor[d], 1);
            cw[pos] = make_int2(sv, __float_as_int(dinv[sv]));
        }
    }
}

// ---------------- shared GEMM pieces ----------------
__device__ __forceinline__ void load_bfr(const unsigned short* __restrict__ Bt,
                                         short8 bfr[2][8], int w, int lr, int ku) {
    const unsigned short* pb = Bt + (size_t)(w * 32 + lr) * NCH + ku * 8;
#pragma unroll
    for (int nf = 0; nf < 2; ++nf)
#pragma unroll
        for (int ks = 0; ks < 8; ++ks)
            bfr[nf][ks] = *(const short8*)(pb + nf * 16 * NCH + ks * 32);
}

__device__ __forceinline__ void gemm_compute_store(const unsigned short* As,
                                                   const short8 bfr[2][8],
                                                   unsigned short* __restrict__ C,
                                                   int M, int t, int w, int lr, int ku) {
    f32x4 acc[2][2];
#pragma unroll
    for (int rf = 0; rf < 2; ++rf)
#pragma unroll
        for (int nf = 0; nf < 2; ++nf) acc[rf][nf] = (f32x4){0.f, 0.f, 0.f, 0.f};

#pragma unroll
    for (int ks = 0; ks < 8; ++ks) {
#pragma unroll
        for (int rf = 0; rf < 2; ++rf) {
            int row = rf * 16 + lr;
            int uu  = (ks * 4 + ku) ^ (row & 7);
            short8 af = *(const short8*)&As[row * 256 + uu * 8];
            acc[rf][0] = __builtin_amdgcn_mfma_f32_16x16x32_bf16(bfr[0][ks], af,
                                                                 acc[rf][0], 0, 0, 0);
            acc[rf][1] = __builtin_amdgcn_mfma_f32_16x16x32_bf16(bfr[1][ks], af,
                                                                 acc[rf][1], 0, 0, 0);
        }
    }

#pragma unroll
    for (int rf = 0; rf < 2; ++rf) {
        int row = t * 32 + rf * 16 + lr;
        if (row < M) {
            unsigned short* pc = C + (size_t)row * NCH + w * 32 + ku * 4;
#pragma unroll
            for (int nf = 0; nf < 2; ++nf) {
                unsigned short us[4];
                us[0] = f2b(acc[rf][nf][0]); us[1] = f2b(acc[rf][nf][1]);
                us[2] = f2b(acc[rf][nf][2]); us[3] = f2b(acc[rf][nf][3]);
                *(int2*)(pc + nf * 16) = *(const int2*)us;
            }
        }
    }
}

// ---------------- layer-2 GEMM: dbuf grid-stride, bf16 A via global_load_lds ----
__global__ __launch_bounds__(512, 4) void k_gemm2(const unsigned short* __restrict__ A,
                                                  const unsigned short* __restrict__ Bt,
                                                  unsigned short* __restrict__ C,
                                                  int M, int tiles) {
    __shared__ unsigned short As[2][32 * 256];
    const int tid  = threadIdx.x;
    const int w    = tid >> 6;
    const int lane = tid & 63;
    const int lr   = lane & 15;
    const int ku   = lane >> 4;

    short8 bfr[2][8];
    load_bfr(Bt, bfr, w, lr, ku);

    const int gu0 = w * 128 + lane;

#define STAGE2(tt, buf) do {                                                  \
        _Pragma("unroll")                                                     \
        for (int j = 0; j < 2; ++j) {                                         \
            int gu = gu0 + j * 64;                                            \
            int r  = gu >> 5;                                                 \
            int u  = gu & 31;                                                 \
            int grow = (tt) * 32 + r; if (grow >= M) grow = M - 1;            \
            const unsigned short* gp = A + (size_t)grow * NCH +               \
                                       ((u ^ (r & 7)) << 3);                  \
            GLOAD_LDS16(gp, (buf) + (size_t)(w * 128 + j * 64) * 8);          \
        }                                                                     \
    } while (0)

    int t = blockIdx.x;
    int cur = 0;
    if (t < tiles) STAGE2(t, As[0]);
    __syncthreads();

    for (; t < tiles; t += gridDim.x) {
        int tn = t + gridDim.x;
        if (tn < tiles) STAGE2(tn, As[cur ^ 1]);
        gemm_compute_store(As[cur], bfr, C, M, t, w, lr, ku);
        __syncthreads();
        cur ^= 1;
    }
#undef STAGE2
}

// ---------------- fused layer-1 GEMM + sharded degree histogram -----------------
__global__ __launch_bounds__(512, 4) void k_g1h(const float* __restrict__ A,
                                                const unsigned short* __restrict__ Bt,
                                                unsigned short* __restrict__ C,
                                                int M, int tiles, int gblocks,
                                                const int* __restrict__ dst, int E,
                                                int* __restrict__ deg,
                                                unsigned shmul) {
    __shared__ unsigned short As[2][32 * 256];
    const int tid = threadIdx.x;

    if (blockIdx.x >= gblocks) {     // ---- hist path (block-uniform branch) ----
        const int b = blockIdx.x - gblocks;
        const int shard  = b & 7;
        const int nchunk = (gridDim.x - gblocks) >> 3;
        const int chunk  = b >> 3;
        const int per = (E + nchunk - 1) / nchunk;
        const int e0 = chunk * per;
        const int e1 = min(e0 + per, E);
        for (int e = e0 + tid; e < e1; e += 512) {
            int d = dst[e];
            if ((int)__umulhi((unsigned)d, shmul) == shard)
                atomicAdd(&deg[d], 1);
        }
        return;
    }

    // ---- gemm1 path (dbuf grid-stride + fused f32->bf16 cast staging) ----
    const int w    = tid >> 6;
    const int lane = tid & 63;
    const int lr   = lane & 15;
    const int ku   = lane >> 4;

    short8 bfr[2][8];
    load_bfr(Bt, bfr, w, lr, ku);

    const int r0_ = tid >> 5,          u0_ = tid & 31;
    const int r1_ = (tid + 512) >> 5,  u1_ = (tid + 512) & 31;

    int t = blockIdx.x;
    int cur = 0;
    if (t < tiles) {                       // prologue: full stage of tile t
        int g0 = t * 32 + r0_; if (g0 >= M) g0 = M - 1;
        int g1 = t * 32 + r1_; if (g1 >= M) g1 = M - 1;
        const float4* pa0 = (const float4*)(A + (size_t)g0 * NCH + u0_ * 8);
        const float4* pa1 = (const float4*)(A + (size_t)g1 * NCH + u1_ * 8);
        float4 a0 = pa0[0], a1 = pa0[1];
        float4 b0 = pa1[0], b1 = pa1[1];
        unsigned short us[8];
        us[0]=f2b(a0.x); us[1]=f2b(a0.y); us[2]=f2b(a0.z); us[3]=f2b(a0.w);
        us[4]=f2b(a1.x); us[5]=f2b(a1.y); us[6]=f2b(a1.z); us[7]=f2b(a1.w);
        *(int4*)&As[0][r0_ * 256 + ((u0_ ^ (r0_ & 7)) << 3)] = *(const int4*)us;
        us[0]=f2b(b0.x); us[1]=f2b(b0.y); us[2]=f2b(b0.z); us[3]=f2b(b0.w);
        us[4]=f2b(b1.x); us[5]=f2b(b1.y); us[6]=f2b(b1.z); us[7]=f2b(b1.w);
        *(int4*)&As[0][r1_ * 256 + ((u1_ ^ (r1_ & 7)) << 3)] = *(const int4*)us;
    }
    __syncthreads();

    for (; t < tiles; t += gblocks) {
        int tn = t + gblocks;
        float4 a0, a1, b0, b1;
        if (tn < tiles) {                  // issue loads early (hide under MFMA)
            int g0 = tn * 32 + r0_; if (g0 >= M) g0 = M - 1;
            int g1 = tn * 32 + r1_; if (g1 >= M) g1 = M - 1;
            const float4* pa0 = (const float4*)(A + (size_t)g0 * NCH + u0_ * 8);
            const float4* pa1 = (const float4*)(A + (size_t)g1 * NCH + u1_ * 8);
            a0 = pa0[0]; a1 = pa0[1];
            b0 = pa1[0]; b1 = pa1[1];
        }

        gemm_compute_store(As[cur], bfr, C, M, t, w, lr, ku);

        if (tn < tiles) {                  // cvt + write late
            unsigned short us[8];
            us[0]=f2b(a0.x); us[1]=f2b(a0.y); us[2]=f2b(a0.z); us[3]=f2b(a0.w);
            us[4]=f2b(a1.x); us[5]=f2b(a1.y); us[6]=f2b(a1.z); us[7]=f2b(a1.w);
            *(int4*)&As[cur ^ 1][r0_ * 256 + ((u0_ ^ (r0_ & 7)) << 3)] = *(const int4*)us;
            us[0]=f2b(b0.x); us[1]=f2b(b0.y); us[2]=f2b(b0.z); us[3]=f2b(b0.w);
            us[4]=f2b(b1.x); us[5]=f2b(b1.y); us[6]=f2b(b1.z); us[7]=f2b(b1.w);
            *(int4*)&As[cur ^ 1][r1_ * 256 + ((u1_ ^ (r1_ & 7)) << 3)] = *(const int4*)us;
        }
        __syncthreads();
        cur ^= 1;
    }
}

// ---------------- aggregation: wave-per-node, 256-thr blocks (4 nodes) ----------
__global__ __launch_bounds__(256) void k_agg_w(const unsigned short* __restrict__ h,
                                               const float* __restrict__ dinv,
                                               const int* __restrict__ row_ptr,
                                               const int2* __restrict__ cw,
                                               const float* __restrict__ bias,
                                               unsigned short* __restrict__ out, int M) {
    int v = blockIdx.x * 4 + (threadIdx.x >> 6);
    if (v >= M) return;                      // no barriers below: safe
    const int lane = threadIdx.x & 63;
    const int half = lane >> 5;
    const int cb   = (lane & 31) << 3;

    float acc[8] = {};
    float dv = dinv[v];

    short8 rs = {};
    if (half == 0) rs = *(const short8*)&h[(size_t)v * NCH + cb];

    int beg = row_ptr[v], end = row_ptr[v + 1];
    int i0 = beg + half * 2;

    short8 r0 = {}, r1 = {};
    float  w0 = 0.f, w1 = 0.f;
    bool b0 = i0 < end, b1 = i0 + 1 < end;
    if (b0) {
        int2 e = cw[i0];
        r0 = *(const short8*)&h[(size_t)e.x * NCH + cb];
        w0 = __int_as_float(e.y);
    }
    if (b1) {
        int2 e = cw[i0 + 1];
        r1 = *(const short8*)&h[(size_t)e.x * NCH + cb];
        w1 = __int_as_float(e.y);
    }

    while (b0) {
        int in = i0 + 4;
        bool n0 = in < end, n1 = in + 1 < end;
        short8 s0 = {}, s1 = {};
        float  x0 = 0.f, x1 = 0.f;
        if (n0) {
            int2 e = cw[in];
            s0 = *(const short8*)&h[(size_t)e.x * NCH + cb];
            x0 = __int_as_float(e.y);
        }
        if (n1) {
            int2 e = cw[in + 1];
            s1 = *(const short8*)&h[(size_t)e.x * NCH + cb];
            x1 = __int_as_float(e.y);
        }
#pragma unroll
        for (int i = 0; i < 8; ++i) acc[i] += w0 * b2f((unsigned short)r0[i]);
#pragma unroll
        for (int i = 0; i < 8; ++i) acc[i] += w1 * b2f((unsigned short)r1[i]);
        r0 = s0; r1 = s1; w0 = x0; w1 = x1; b0 = n0; b1 = n1; i0 = in;
    }

    if (half == 0) {
#pragma unroll
        for (int i = 0; i < 8; ++i) acc[i] += dv * b2f((unsigned short)rs[i]);
    }

#pragma unroll
    for (int i = 0; i < 8; ++i) acc[i] += __shfl_xor(acc[i], 32, 64);

    if (half == 0) {
        f32x4 bl = *(const f32x4*)&bias[cb];
        f32x4 bh = *(const f32x4*)&bias[cb + 4];
        unsigned short us[8];
#pragma unroll
        for (int i = 0; i < 8; ++i) {
            float b = (i < 4) ? bl[i] : bh[i - 4];
            us[i] = f2b(fmaxf(dv * acc[i] + b, 0.0f));
        }
        *(int4*)&out[(size_t)v * NCH + cb] = *(const int4*)us;
    }
}

// ---------------- mean pool, two-phase ----------------
__device__ __forceinline__ int lower_bound_i(const int* a, int n, int key) {
    int lo = 0, hi = n;
    while (lo < hi) {
        int mid = (lo + hi) >> 1;
        if (a[mid] < key) lo = mid + 1; else hi = mid;
    }
    return lo;
}

__global__ __launch_bounds__(64) void k_pool_a(const unsigned short* __restrict__ a,
                                               const int* __restrict__ batch,
                                               float* __restrict__ partial, int N) {
    int g = blockIdx.x, s = blockIdx.y;
    const int lane = threadIdx.x;
    const int half = lane >> 5;
    const int cb   = (lane & 31) << 3;

    int lo = lower_bound_i(batch, N, g);
    int hi = lower_bound_i(batch, N, g + 1);
    int cnt = hi - lo;
    int len = (cnt + NS - 1) / NS;
    int rlo = lo + s * len;
    int rhi = min(rlo + len, hi);

    float acc[8] = {};
    for (int r = rlo + half; r < rhi; r += 2) {
        short8 hv = *(const short8*)&a[(size_t)r * NCH + cb];
#pragma unroll
        for (int i = 0; i < 8; ++i) acc[i] += b2f((unsigned short)hv[i]);
    }
#pragma unroll
    for (int i = 0; i < 8; ++i) acc[i] += __shfl_xor(acc[i], 32, 64);

    if (half == 0) {
        float* p = partial + ((size_t)g * NS + s) * NCH + cb;
        *(f32x4*)p       = (f32x4){acc[0], acc[1], acc[2], acc[3]};
        *(f32x4*)(p + 4) = (f32x4){acc[4], acc[5], acc[6], acc[7]};
    }
}

__global__ __launch_bounds__(256) void k_pool_b(const float* __restrict__ partial,
                                                const int* __restrict__ batch,
                                                float* __restrict__ out, int N) {
    int g = blockIdx.x, ch = threadIdx.x;
    int lo = lower_bound_i(batch, N, g);
    int hi = lower_bound_i(batch, N, g + 1);
    float s = 0.0f;
#pragma unroll
    for (int k = 0; k < NS; ++k)
        s += partial[((size_t)g * NS + k) * NCH + ch];
    out[(size_t)g * NCH + ch] = s / (float)max(hi - lo, 1);
}

// ---------------- host ----------------
extern "C" void kernel_launch(void* const* d_in, const int* in_sizes, int n_in,
                              void* d_out, int out_size, void* d_ws, size_t ws_size,
                              hipStream_t stream) {
    const float* x     = (const float*)d_in[0];
    const int*   ei    = (const int*)d_in[1];
    const int*   batch = (const int*)d_in[2];
    const float* W1    = (const float*)d_in[3];
    const float* b1    = (const float*)d_in[4];
    const float* W2    = (const float*)d_in[5];
    const float* b2    = (const float*)d_in[6];
    float* out = (float*)d_out;

    const int M = in_sizes[0] / NCH;   // 50000
    const int E = in_sizes[1] / 2;     // 800000
    const int* src = ei;
    const int* dst = ei + E;

    char* w = (char*)d_ws;
    auto alloc = [&](size_t bytes) -> void* {
        void* p = (void*)w;
        w += (bytes + 255) & ~(size_t)255;
        return p;
    };
    int*   deg     = (int*)alloc((size_t)M * 4);
    float* dinv    = (float*)alloc((size_t)M * 4);
    int*   row_ptr = (int*)alloc((size_t)(M + 1) * 4);
    int*   cursor  = (int*)alloc((size_t)M * 4);
    int*   bsum    = (int*)alloc(64 * 4);
    int2*  cw      = (int2*)alloc((size_t)E * 8);
    unsigned short* bufP = (unsigned short*)alloc((size_t)M * NCH * 2);
    unsigned short* bufQ = (unsigned short*)alloc((size_t)M * NCH * 2);
    unsigned short* Wt1  = (unsigned short*)alloc((size_t)NCH * NCH * 2);
    unsigned short* Wt2  = (unsigned short*)alloc((size_t)NCH * NCH * 2);
    float* partial = (float*)alloc((size_t)128 * NS * NCH * 4);

    const int nb = (M + 1023) / 1024;
    const unsigned shmul = (unsigned)(((8ull << 32) + M - 1) / (unsigned long long)M);
    const int tiles = (M + 31) / 32;   // 1563
    const int gblocks = 512;           // gemm1 blocks (mult of 8)
    const int hblocks = 2048;          // hist blocks (256 chunks x 8 shards)

    // W transpose-cast + deg zeroing (replaces memset)
    k_castT<<<dim3(256, 2), 256, 0, stream>>>(W1, W2, Wt1, Wt2, deg, M);

    // layer-1 GEMM fused with degree histogram
    k_g1h<<<gblocks + hblocks, 512, 0, stream>>>(x, Wt1, bufP, M, tiles, gblocks,
                                                 dst, E, deg, shmul);
    k_scan_blk<<<nb, 256, 0, stream>>>(deg, row_ptr, bsum, M);
    k_finalize<<<(M + 255) / 256, 256, 0, stream>>>(deg, row_ptr, bsum, cursor,
                                                    dinv, M, E);
    k_scatter_sh<<<2048, 256, 0, stream>>>(src, dst, E, cursor, dinv, cw, shmul);

    const int agrid = (M + 3) / 4;

    k_agg_w<<<agrid, 256, 0, stream>>>(bufP, dinv, row_ptr, cw, b1, bufQ, M);
    // layer 2
    k_gemm2<<<512, 512, 0, stream>>>(bufQ, Wt2, bufP, M, tiles);
    k_agg_w<<<agrid, 256, 0, stream>>>(bufP, dinv, row_ptr, cw, b2, bufQ, M);
    // pool
    k_pool_a<<<dim3(128, NS), 64, 0, stream>>>(bufQ, batch, partial, M);
    k_pool_b<<<128, 256, 0, stream>>>(partial, batch, out, M);
}